// Round 1
// baseline (493.817 us; speedup 1.0000x reference)
//
#include <hip/hip_runtime.h>
#include <math.h>

// Problem constants (unit_gcn): N=64, C=64, T=300, V=25, S=3
//
// ws float layout:
//   [2048, 4096)   : stats, 16 replicas x (sum[64], sumsq[64])
//   [4096, 4224)   : (unused this round)
//   [4352, 10496)  : W-frag table ushort[12288]: frag f=((s*2+kt)*4+wv), elem lane*8+j
//   [10496, 12032) : A-frag table ushort[3072]:  frag f=(s*2+nt2)
//   byte 65536+    : ypre bf16, natural [n][o][t][w], 61.44 MB
//
// R7 theory: k_main was latency-bound (MfmaUtil 5.3%, VALU 14.5%, HBM 13%,
// Occ 42%) on the per-(s,t) Z LDS round-trip (write 8 u16 -> lgkm drain ->
// read b128) plus low residency. Fix: swap GEMM1 operands so Z^T lands with
// o lane-local; rebuild GEMM2's A-frag in registers via 8 bpermute + 4
// cndmask (bit-identical f2bf packing). Zl deleted -> LDS 22016->16640,
// launch_bounds (256,6). k_stats folded into k_bnrelu.

typedef __attribute__((ext_vector_type(8))) short bf16x8;
typedef __attribute__((ext_vector_type(4))) float f32x4;

__device__ inline ushort f2bf(float f) {
    union { float f; unsigned u; } v; v.f = f;
    unsigned r = v.u + 0x7fffu + ((v.u >> 16) & 1u);
    return (ushort)(r >> 16);
}
__device__ inline float bf2f(ushort h) {
    union { unsigned u; float f; } v; v.u = ((unsigned)h) << 16;
    return v.f;
}

// ---------------------------------------------------------------------------
// K1: 8 blocks. Normalize A (LDS), zero stats (block 0), build frag tables.
// ---------------------------------------------------------------------------
__global__ __launch_bounds__(256) void k_prep(const float* __restrict__ PA,
                                              const float* __restrict__ W,
                                              float* __restrict__ ws) {
    __shared__ float Al[1875];
    const int tid = threadIdx.x;
    const int bid = blockIdx.x;
    for (int i = tid; i < 1875; i += 256) Al[i] = PA[i];
    if (bid == 0)
        for (int i = tid; i < 2048; i += 256) ws[2048 + i] = 0.0f;
    __syncthreads();
    if (tid < 75) {
        int s = tid / 25, w = tid - s * 25;
        float ss = 0.0f;
        for (int v = 0; v < 25; ++v) {
            float p = Al[s * 625 + v * 25 + w];
            ss += p * p;
        }
        float inv = 1.0f / (sqrtf(ss) + 1e-4f);
        for (int v = 0; v < 25; ++v) Al[s * 625 + v * 25 + w] *= inv;
    }
    __syncthreads();
    int idx = bid * 256 + tid;
    if (idx < 1536) {  // W-frag: W[s][o=wv*16+col][c=kt*32+quad*8+j]
        ushort* wt = (ushort*)(ws + 4352);
        int lane = idx & 63, rest = idx >> 6;
        int wv = rest & 3, sk = rest >> 2;
        int kt = sk & 1, s = sk >> 1;
        int col = lane & 15, quad = lane >> 4;
        const float* wp = W + s * 4096 + (wv * 16 + col) * 64 + kt * 32 + quad * 8;
#pragma unroll
        for (int j = 0; j < 8; ++j) wt[idx * 8 + j] = f2bf(wp[j]);
    } else if (idx < 1920) {  // A-frag: A[s][v=quad*8+j][w=nt2*16+col], OOB->0
        ushort* at = (ushort*)(ws + 10496);
        int a = idx - 1536;
        int lane = a & 63, rest = a >> 6;
        int nt2 = rest & 1, s = rest >> 1;
        int col = lane & 15, quad = lane >> 4;
        int w = nt2 * 16 + col;
#pragma unroll
        for (int j = 0; j < 8; ++j) {
            int v = quad * 8 + j;
            float av = (v < 25 && w < 25) ? Al[s * 625 + v * 25 + w] : 0.0f;
            at[a * 8 + j] = f2bf(av);
        }
    }
}

// ---------------------------------------------------------------------------
// K2: per block one n, 4 t-steps (grid 75 x 64).
//  GEMM1 (per s,t), operands swapped: zA/zB = mfma(x_frag, w_frag) gives
//    Z^T[v][o]: o = strip+col (lane-local!), v = (quad*4+r) (+16 for zB).
//  Register re-layout: pack f2bf pairs, 8 bpermute + 4 cndmask -> zf frag
//    with elem j = Z[o=strip+col][v=quad*8+j]. No LDS round-trip.
//  GEMM2 (per s,t): yacc[t] += zf * A_s  (K=25->32 pad; zB garbage rows
//    v>=25 are killed by A-frag zeros).
// LDS: Xl [112 rows][72] bf16 only (16.6 KB total) -> up to 9 blocks/CU.
// ---------------------------------------------------------------------------
__global__ __launch_bounds__(256, 6) void k_main7(const float* __restrict__ x,
                                                  const float* __restrict__ ws,
                                                  ushort* __restrict__ ypre,
                                                  float* __restrict__ stats) {
    __shared__ __align__(16) ushort Xl[112 * 72];
    __shared__ float sst[128];

    const int tid = threadIdx.x;
    const int wv = tid >> 6;
    const int lane = tid & 63;
    const int col = lane & 15;
    const int quad = lane >> 4;
    const int strip = wv << 4;
    const int n = blockIdx.y;
    const int t0 = blockIdx.x * 4;

    // stage X (float4 loads): x[n, c, t0*25 + tv] -> Xl[tv*72 + c]
    {
        const float* xr = x + n * 480000 + t0 * 25;
        const int c = tid >> 2, part = tid & 3;
        const float4* row = (const float4*)(xr + c * 7500);
        for (int j = part; j < 25; j += 4) {
            float4 v4 = row[j];
            ushort* dst = &Xl[(j * 4) * 72 + c];
            dst[0]   = f2bf(v4.x);
            dst[72]  = f2bf(v4.y);
            dst[144] = f2bf(v4.z);
            dst[216] = f2bf(v4.w);
        }
        for (int i = tid; i < 864; i += 256) Xl[7200 + i] = 0;  // rows 100..111
    }
    __syncthreads();

    const ushort* wt = (const ushort*)(ws + 4352);
    const ushort* at = (const ushort*)(ws + 10496);

    // bpermute source lanes for the quad re-layout (same col, quads 2q, 2q+1)
    const int s0l = col + ((quad & 1) << 5);
    const int s1l = s0l + 16;
    const bool hiq = quad >= 2;

    f32x4 yacc[4][2];
#pragma unroll
    for (int t = 0; t < 4; ++t)
#pragma unroll
        for (int j = 0; j < 2; ++j) yacc[t][j] = (f32x4){0.f, 0.f, 0.f, 0.f};

    for (int s = 0; s < 3; ++s) {
        // reload only the current-s fragments (16 live regs, L3-hot)
        bf16x8 wf0 = *(const bf16x8*)&wt[(((s * 2 + 0) * 4 + wv) * 64 + lane) * 8];
        bf16x8 wf1 = *(const bf16x8*)&wt[(((s * 2 + 1) * 4 + wv) * 64 + lane) * 8];
        bf16x8 af0 = *(const bf16x8*)&at[((s * 2 + 0) * 64 + lane) * 8];
        bf16x8 af1 = *(const bf16x8*)&at[((s * 2 + 1) * 64 + lane) * 8];
#pragma unroll
        for (int t = 0; t < 4; ++t) {
            const int r0 = (t * 25 + col) * 72 + (quad << 3);
            const int r1 = r0 + 16 * 72;
            bf16x8 x00 = *(const bf16x8*)&Xl[r0];
            bf16x8 x01 = *(const bf16x8*)&Xl[r0 + 32];
            bf16x8 x10 = *(const bf16x8*)&Xl[r1];
            bf16x8 x11 = *(const bf16x8*)&Xl[r1 + 32];
            // GEMM1 swapped: D[m=v][n=o] = X^T * W^T = Z^T   (bit-identical MACs)
            f32x4 zA = (f32x4){0.f, 0.f, 0.f, 0.f};
            f32x4 zB = (f32x4){0.f, 0.f, 0.f, 0.f};
            zA = __builtin_amdgcn_mfma_f32_16x16x32_bf16(x00, wf0, zA, 0, 0, 0);
            zA = __builtin_amdgcn_mfma_f32_16x16x32_bf16(x01, wf1, zA, 0, 0, 0);
            zB = __builtin_amdgcn_mfma_f32_16x16x32_bf16(x10, wf0, zB, 0, 0, 0);
            zB = __builtin_amdgcn_mfma_f32_16x16x32_bf16(x11, wf1, zB, 0, 0, 0);
            // pack with the same f2bf rounding as the old LDS path
            unsigned pa0 = (unsigned)f2bf(zA[0]) | ((unsigned)f2bf(zA[1]) << 16);
            unsigned pa1 = (unsigned)f2bf(zA[2]) | ((unsigned)f2bf(zA[3]) << 16);
            unsigned pb0 = (unsigned)f2bf(zB[0]) | ((unsigned)f2bf(zB[1]) << 16);
            unsigned pb1 = (unsigned)f2bf(zB[2]) | ((unsigned)f2bf(zB[3]) << 16);
            // quad re-layout: dest (col,q) word w: v-pairs (8q+2w, 8q+2w+1)
            //   words 0,1 from lane col+16*((2q)&3); words 2,3 from +16
            //   q<2 -> zA-pack, q>=2 -> zB-pack (selected on DEST side)
            unsigned ga0 = __shfl(pa0, s0l);
            unsigned ga1 = __shfl(pa1, s0l);
            unsigned ga2 = __shfl(pa0, s1l);
            unsigned ga3 = __shfl(pa1, s1l);
            unsigned gb0 = __shfl(pb0, s0l);
            unsigned gb1 = __shfl(pb1, s0l);
            unsigned gb2 = __shfl(pb0, s1l);
            unsigned gb3 = __shfl(pb1, s1l);
            union { unsigned u[4]; bf16x8 v; } zf;
            zf.u[0] = hiq ? gb0 : ga0;
            zf.u[1] = hiq ? gb1 : ga1;
            zf.u[2] = hiq ? gb2 : ga2;
            zf.u[3] = hiq ? gb3 : ga3;
            yacc[t][0] = __builtin_amdgcn_mfma_f32_16x16x32_bf16(zf.v, af0, yacc[t][0], 0, 0, 0);
            yacc[t][1] = __builtin_amdgcn_mfma_f32_16x16x32_bf16(zf.v, af1, yacc[t][1], 0, 0, 0);
        }
    }

    // epilogue: D layout col(lane&15)=w(+16*nt2), row(quad*4+r)=o offset
    float ssum[4] = {0.f, 0.f, 0.f, 0.f}, ssq[4] = {0.f, 0.f, 0.f, 0.f};
    const int obase = strip + (quad << 2);
#pragma unroll
    for (int t = 0; t < 4; ++t)
#pragma unroll
        for (int nt2 = 0; nt2 < 2; ++nt2) {
            int w = nt2 * 16 + col;
            if (w < 25) {
                ushort* yp = ypre + n * 480000 + obase * 7500 + (t0 + t) * 25 + w;
                f32x4 f = yacc[t][nt2];
#pragma unroll
                for (int r = 0; r < 4; ++r) {
                    float yv = f[r];
                    yp[r * 7500] = f2bf(yv);
                    ssum[r] += yv;
                    ssq[r] = fmaf(yv, yv, ssq[r]);
                }
            }
        }
#pragma unroll
    for (int r = 0; r < 4; ++r) {
        float a = ssum[r], b = ssq[r];
        for (int m = 1; m < 16; m <<= 1) {  // reduce over the 16 w-lanes
            a += __shfl_xor(a, m, 64);
            b += __shfl_xor(b, m, 64);
        }
        if (col == 0) {  // unique (wv,quad,r) -> unique o
            sst[obase + r] = a;
            sst[64 + obase + r] = b;
        }
    }
    __syncthreads();
    const int rep = (blockIdx.x + blockIdx.y) & 15;
    if (tid < 128) atomicAdd(&stats[rep * 128 + tid], sst[tid]);
}

// ---------------------------------------------------------------------------
// K3: out = relu(sc[o]*bf2f(ypre) + sh[o] + x). Plane-mapped: block = one
// (n,o) plane (4096 blocks). BN finalize folded in (reads the 16 replica
// stats lines for its own o; was a separate 1-block kernel = launch bubble).
// ---------------------------------------------------------------------------
__global__ __launch_bounds__(256) void k_bnrelu_b(const float* __restrict__ x,
                                                  const ushort* __restrict__ ypre,
                                                  const float* __restrict__ stats,
                                                  const float* __restrict__ gamma,
                                                  const float* __restrict__ beta,
                                                  float* __restrict__ out) {
    __shared__ float bsc[2];
    const int plane = blockIdx.x;  // n*64 + o
    const int o = plane & 63;
    const int tid = threadIdx.x;
    if (tid < 16) {
        float su = stats[tid * 128 + o];
        float sq = stats[tid * 128 + 64 + o];
#pragma unroll
        for (int m = 1; m < 16; m <<= 1) {
            su += __shfl_xor(su, m, 64);
            sq += __shfl_xor(sq, m, 64);
        }
        if (tid == 0) {
            const float invn = 1.0f / 480000.0f;  // N*T*V
            float mean = su * invn;
            float var = sq * invn - mean * mean;
            float sc = gamma[o] * rsqrtf(var + 1e-5f);
            bsc[0] = sc;
            bsc[1] = beta[o] - mean * sc;
        }
    }
    __syncthreads();
    const float sc = bsc[0], sh = bsc[1];
    const ushort* yp = ypre + plane * 7500;
    const float4* xp = (const float4*)(x + plane * 7500);
    float4* op = (float4*)(out + plane * 7500);
    for (int j = tid; j < 1875; j += 256) {
        ushort4 yv = ((const ushort4*)yp)[j];
        float4 xx = xp[j];
        float4 r;
        r.x = fmaxf(fmaf(bf2f(yv.x), sc, sh) + xx.x, 0.0f);
        r.y = fmaxf(fmaf(bf2f(yv.y), sc, sh) + xx.y, 0.0f);
        r.z = fmaxf(fmaf(bf2f(yv.z), sc, sh) + xx.z, 0.0f);
        r.w = fmaxf(fmaf(bf2f(yv.w), sc, sh) + xx.w, 0.0f);
        op[j] = r;
    }
}

// ---------------------------------------------------------------------------
extern "C" void kernel_launch(void* const* d_in, const int* in_sizes, int n_in,
                              void* d_out, int out_size, void* d_ws, size_t ws_size,
                              hipStream_t stream) {
    const float* x = (const float*)d_in[0];
    const float* PA = (const float*)d_in[1];
    const float* W = (const float*)d_in[2];
    // d_in[3] = b : cancels through training-mode BN -> unused
    const float* gamma = (const float*)d_in[4];
    const float* beta = (const float*)d_in[5];
    float* wsf = (float*)d_ws;
    float* out = (float*)d_out;
    ushort* ypre = (ushort*)((char*)d_ws + 65536);

    k_prep<<<8, 256, 0, stream>>>(PA, W, wsf);
    dim3 g(75, 64);
    k_main7<<<g, 256, 0, stream>>>(x, wsf, ypre, wsf + 2048);
    k_bnrelu_b<<<4096, 256, 0, stream>>>(x, ypre, wsf + 2048, gamma, beta, out);
}

// Round 3
// 317.932 us; speedup vs baseline: 1.5532x; 1.5532x over previous
//
#include <hip/hip_runtime.h>
#include <math.h>

// Problem constants (unit_gcn): N=64, C=64, T=300, V=25, S=3
//
// ws float layout:
//   [2048, 4096)   : stats, 16 replicas x (sum[64], sumsq[64])
//   [4352, 10496)  : W-frag table ushort[12288]: frag f=((s*2+kt)*4+wv), elem lane*8+j
//   [10496, 12032) : A-frag table ushort[3072]:  frag f=(s*2+nt2)
//   byte 65536+    : ypre bf16, natural [n][o][t][w], 61.44 MB
//
// R9 = R8 with the nontemporal builtins fixed: clang requires ext_vector
// pointers (HIP_vector_type float4/ushort4 rejected). Theory unchanged:
// R7's (256,6) bound forced 40-VGPR cap -> ~100 floats/thread scratch spill
// (FETCH 85->385 MB, WRITE 89->574 MB). Live regs ~90 -> (256,4) fits with
// zero spill. Keep operand-swapped GEMM1 + shfl Z re-layout (no Z LDS
// round-trip; LDS 16.9 KB). k_bnrelu streams are touch-once -> nontemporal.

typedef __attribute__((ext_vector_type(8))) short bf16x8;
typedef __attribute__((ext_vector_type(4))) float f32x4;
typedef __attribute__((ext_vector_type(4))) ushort u16x4;

__device__ inline ushort f2bf(float f) {
    union { float f; unsigned u; } v; v.f = f;
    unsigned r = v.u + 0x7fffu + ((v.u >> 16) & 1u);
    return (ushort)(r >> 16);
}
__device__ inline float bf2f(ushort h) {
    union { unsigned u; float f; } v; v.u = ((unsigned)h) << 16;
    return v.f;
}

// ---------------------------------------------------------------------------
// K1: 8 blocks. Normalize A (LDS), zero stats (block 0), build frag tables.
// ---------------------------------------------------------------------------
__global__ __launch_bounds__(256) void k_prep(const float* __restrict__ PA,
                                              const float* __restrict__ W,
                                              float* __restrict__ ws) {
    __shared__ float Al[1875];
    const int tid = threadIdx.x;
    const int bid = blockIdx.x;
    for (int i = tid; i < 1875; i += 256) Al[i] = PA[i];
    if (bid == 0)
        for (int i = tid; i < 2048; i += 256) ws[2048 + i] = 0.0f;
    __syncthreads();
    if (tid < 75) {
        int s = tid / 25, w = tid - s * 25;
        float ss = 0.0f;
        for (int v = 0; v < 25; ++v) {
            float p = Al[s * 625 + v * 25 + w];
            ss += p * p;
        }
        float inv = 1.0f / (sqrtf(ss) + 1e-4f);
        for (int v = 0; v < 25; ++v) Al[s * 625 + v * 25 + w] *= inv;
    }
    __syncthreads();
    int idx = bid * 256 + tid;
    if (idx < 1536) {  // W-frag: W[s][o=wv*16+col][c=kt*32+quad*8+j]
        ushort* wt = (ushort*)(ws + 4352);
        int lane = idx & 63, rest = idx >> 6;
        int wv = rest & 3, sk = rest >> 2;
        int kt = sk & 1, s = sk >> 1;
        int col = lane & 15, quad = lane >> 4;
        const float* wp = W + s * 4096 + (wv * 16 + col) * 64 + kt * 32 + quad * 8;
#pragma unroll
        for (int j = 0; j < 8; ++j) wt[idx * 8 + j] = f2bf(wp[j]);
    } else if (idx < 1920) {  // A-frag: A[s][v=quad*8+j][w=nt2*16+col], OOB->0
        ushort* at = (ushort*)(ws + 10496);
        int a = idx - 1536;
        int lane = a & 63, rest = a >> 6;
        int nt2 = rest & 1, s = rest >> 1;
        int col = lane & 15, quad = lane >> 4;
        int w = nt2 * 16 + col;
#pragma unroll
        for (int j = 0; j < 8; ++j) {
            int v = quad * 8 + j;
            float av = (v < 25 && w < 25) ? Al[s * 625 + v * 25 + w] : 0.0f;
            at[a * 8 + j] = f2bf(av);
        }
    }
}

// ---------------------------------------------------------------------------
// K2: per block one n, 4 t-steps (grid 75 x 64).
//  GEMM1 (per s,t), operands swapped: zA/zB = mfma(x_frag, w_frag) gives
//    Z^T[v][o]: o = strip+col (lane-local!), v = (quad*4+r) (+16 for zB).
//  Register re-layout: pack f2bf pairs, 8 shfl + 4 cndmask -> zf frag
//    with elem j = Z[o=strip+col][v=quad*8+j]. No LDS round-trip.
//  GEMM2 (per s,t): yacc[t] += zf * A_s  (K=25->32 pad; zB garbage rows
//    v>=25 are killed by A-frag zeros).
// LDS: Xl [112 rows][72] bf16 only (16.6 KB) -> LDS never the limiter.
// launch_bounds (256,4): 128-VGPR cap, live ~90 -> no spill (R7 lesson).
// ---------------------------------------------------------------------------
__global__ __launch_bounds__(256, 4) void k_main8(const float* __restrict__ x,
                                                  const float* __restrict__ ws,
                                                  ushort* __restrict__ ypre,
                                                  float* __restrict__ stats) {
    __shared__ __align__(16) ushort Xl[112 * 72];
    __shared__ float sst[128];

    const int tid = threadIdx.x;
    const int wv = tid >> 6;
    const int lane = tid & 63;
    const int col = lane & 15;
    const int quad = lane >> 4;
    const int strip = wv << 4;
    const int n = blockIdx.y;
    const int t0 = blockIdx.x * 4;

    // stage X (float4 loads): x[n, c, t0*25 + tv] -> Xl[tv*72 + c]
    {
        const float* xr = x + n * 480000 + t0 * 25;
        const int c = tid >> 2, part = tid & 3;
        const float4* row = (const float4*)(xr + c * 7500);
        for (int j = part; j < 25; j += 4) {
            float4 v4 = row[j];
            ushort* dst = &Xl[(j * 4) * 72 + c];
            dst[0]   = f2bf(v4.x);
            dst[72]  = f2bf(v4.y);
            dst[144] = f2bf(v4.z);
            dst[216] = f2bf(v4.w);
        }
        for (int i = tid; i < 864; i += 256) Xl[7200 + i] = 0;  // rows 100..111
    }
    __syncthreads();

    const ushort* wt = (const ushort*)(ws + 4352);
    const ushort* at = (const ushort*)(ws + 10496);

    // shfl source lanes for the quad re-layout (same col, quads 2q, 2q+1)
    const int s0l = col + ((quad & 1) << 5);
    const int s1l = s0l + 16;
    const bool hiq = quad >= 2;

    f32x4 yacc[4][2];
#pragma unroll
    for (int t = 0; t < 4; ++t)
#pragma unroll
        for (int j = 0; j < 2; ++j) yacc[t][j] = (f32x4){0.f, 0.f, 0.f, 0.f};

    for (int s = 0; s < 3; ++s) {
        // reload only the current-s fragments (16 live regs, L3-hot)
        bf16x8 wf0 = *(const bf16x8*)&wt[(((s * 2 + 0) * 4 + wv) * 64 + lane) * 8];
        bf16x8 wf1 = *(const bf16x8*)&wt[(((s * 2 + 1) * 4 + wv) * 64 + lane) * 8];
        bf16x8 af0 = *(const bf16x8*)&at[((s * 2 + 0) * 64 + lane) * 8];
        bf16x8 af1 = *(const bf16x8*)&at[((s * 2 + 1) * 64 + lane) * 8];
#pragma unroll
        for (int t = 0; t < 4; ++t) {
            const int r0 = (t * 25 + col) * 72 + (quad << 3);
            const int r1 = r0 + 16 * 72;
            bf16x8 x00 = *(const bf16x8*)&Xl[r0];
            bf16x8 x01 = *(const bf16x8*)&Xl[r0 + 32];
            bf16x8 x10 = *(const bf16x8*)&Xl[r1];
            bf16x8 x11 = *(const bf16x8*)&Xl[r1 + 32];
            // GEMM1 swapped: D[m=v][n=o] = X^T * W^T = Z^T  (bit-identical MACs)
            f32x4 zA = (f32x4){0.f, 0.f, 0.f, 0.f};
            f32x4 zB = (f32x4){0.f, 0.f, 0.f, 0.f};
            zA = __builtin_amdgcn_mfma_f32_16x16x32_bf16(x00, wf0, zA, 0, 0, 0);
            zA = __builtin_amdgcn_mfma_f32_16x16x32_bf16(x01, wf1, zA, 0, 0, 0);
            zB = __builtin_amdgcn_mfma_f32_16x16x32_bf16(x10, wf0, zB, 0, 0, 0);
            zB = __builtin_amdgcn_mfma_f32_16x16x32_bf16(x11, wf1, zB, 0, 0, 0);
            // pack with the same f2bf rounding as the old LDS path
            unsigned pa0 = (unsigned)f2bf(zA[0]) | ((unsigned)f2bf(zA[1]) << 16);
            unsigned pa1 = (unsigned)f2bf(zA[2]) | ((unsigned)f2bf(zA[3]) << 16);
            unsigned pb0 = (unsigned)f2bf(zB[0]) | ((unsigned)f2bf(zB[1]) << 16);
            unsigned pb1 = (unsigned)f2bf(zB[2]) | ((unsigned)f2bf(zB[3]) << 16);
            // quad re-layout: dest (col,q) word w: v-pairs (8q+2w, 8q+2w+1)
            unsigned ga0 = __shfl(pa0, s0l);
            unsigned ga1 = __shfl(pa1, s0l);
            unsigned ga2 = __shfl(pa0, s1l);
            unsigned ga3 = __shfl(pa1, s1l);
            unsigned gb0 = __shfl(pb0, s0l);
            unsigned gb1 = __shfl(pb1, s0l);
            unsigned gb2 = __shfl(pb0, s1l);
            unsigned gb3 = __shfl(pb1, s1l);
            union { unsigned u[4]; bf16x8 v; } zf;
            zf.u[0] = hiq ? gb0 : ga0;
            zf.u[1] = hiq ? gb1 : ga1;
            zf.u[2] = hiq ? gb2 : ga2;
            zf.u[3] = hiq ? gb3 : ga3;
            yacc[t][0] = __builtin_amdgcn_mfma_f32_16x16x32_bf16(zf.v, af0, yacc[t][0], 0, 0, 0);
            yacc[t][1] = __builtin_amdgcn_mfma_f32_16x16x32_bf16(zf.v, af1, yacc[t][1], 0, 0, 0);
        }
    }

    // epilogue: D layout col(lane&15)=w(+16*nt2), row(quad*4+r)=o offset
    float ssum[4] = {0.f, 0.f, 0.f, 0.f}, ssq[4] = {0.f, 0.f, 0.f, 0.f};
    const int obase = strip + (quad << 2);
#pragma unroll
    for (int t = 0; t < 4; ++t)
#pragma unroll
        for (int nt2 = 0; nt2 < 2; ++nt2) {
            int w = nt2 * 16 + col;
            if (w < 25) {
                ushort* yp = ypre + n * 480000 + obase * 7500 + (t0 + t) * 25 + w;
                f32x4 f = yacc[t][nt2];
#pragma unroll
                for (int r = 0; r < 4; ++r) {
                    float yv = f[r];
                    yp[r * 7500] = f2bf(yv);
                    ssum[r] += yv;
                    ssq[r] = fmaf(yv, yv, ssq[r]);
                }
            }
        }
#pragma unroll
    for (int r = 0; r < 4; ++r) {
        float a = ssum[r], b = ssq[r];
        for (int m = 1; m < 16; m <<= 1) {  // reduce over the 16 w-lanes
            a += __shfl_xor(a, m, 64);
            b += __shfl_xor(b, m, 64);
        }
        if (col == 0) {  // unique (wv,quad,r) -> unique o
            sst[obase + r] = a;
            sst[64 + obase + r] = b;
        }
    }
    __syncthreads();
    const int rep = (blockIdx.x + blockIdx.y) & 15;
    if (tid < 128) atomicAdd(&stats[rep * 128 + tid], sst[tid]);
}

// ---------------------------------------------------------------------------
// K3: out = relu(sc[o]*bf2f(ypre) + sh[o] + x). Plane-mapped: block = one
// (n,o) plane (4096 blocks). BN finalize folded in. All three streams are
// touched exactly once globally -> nontemporal (ext_vector ptrs: clang
// rejects HIP_vector_type for the NT builtins — R8 compile failure).
// ---------------------------------------------------------------------------
__global__ __launch_bounds__(256) void k_bnrelu_c(const float* __restrict__ x,
                                                  const ushort* __restrict__ ypre,
                                                  const float* __restrict__ stats,
                                                  const float* __restrict__ gamma,
                                                  const float* __restrict__ beta,
                                                  float* __restrict__ out) {
    __shared__ float bsc[2];
    const int plane = blockIdx.x;  // n*64 + o
    const int o = plane & 63;
    const int tid = threadIdx.x;
    if (tid < 16) {
        float su = stats[tid * 128 + o];
        float sq = stats[tid * 128 + 64 + o];
#pragma unroll
        for (int m = 1; m < 16; m <<= 1) {
            su += __shfl_xor(su, m, 64);
            sq += __shfl_xor(sq, m, 64);
        }
        if (tid == 0) {
            const float invn = 1.0f / 480000.0f;  // N*T*V
            float mean = su * invn;
            float var = sq * invn - mean * mean;
            float sc = gamma[o] * rsqrtf(var + 1e-5f);
            bsc[0] = sc;
            bsc[1] = beta[o] - mean * sc;
        }
    }
    __syncthreads();
    const float sc = bsc[0], sh = bsc[1];
    const u16x4* yp = (const u16x4*)(ypre + plane * 7500);
    const f32x4* xp = (const f32x4*)(x + plane * 7500);
    f32x4* op = (f32x4*)(out + plane * 7500);
    for (int j = tid; j < 1875; j += 256) {
        u16x4 yv = __builtin_nontemporal_load(&yp[j]);
        f32x4 xx = __builtin_nontemporal_load(&xp[j]);
        f32x4 r;
        r.x = fmaxf(fmaf(bf2f(yv.x), sc, sh) + xx.x, 0.0f);
        r.y = fmaxf(fmaf(bf2f(yv.y), sc, sh) + xx.y, 0.0f);
        r.z = fmaxf(fmaf(bf2f(yv.z), sc, sh) + xx.z, 0.0f);
        r.w = fmaxf(fmaf(bf2f(yv.w), sc, sh) + xx.w, 0.0f);
        __builtin_nontemporal_store(r, &op[j]);
    }
}

// ---------------------------------------------------------------------------
extern "C" void kernel_launch(void* const* d_in, const int* in_sizes, int n_in,
                              void* d_out, int out_size, void* d_ws, size_t ws_size,
                              hipStream_t stream) {
    const float* x = (const float*)d_in[0];
    const float* PA = (const float*)d_in[1];
    const float* W = (const float*)d_in[2];
    // d_in[3] = b : cancels through training-mode BN -> unused
    const float* gamma = (const float*)d_in[4];
    const float* beta = (const float*)d_in[5];
    float* wsf = (float*)d_ws;
    float* out = (float*)d_out;
    ushort* ypre = (ushort*)((char*)d_ws + 65536);

    k_prep<<<8, 256, 0, stream>>>(PA, W, wsf);
    dim3 g(75, 64);
    k_main8<<<g, 256, 0, stream>>>(x, wsf, ypre, wsf + 2048);
    k_bnrelu_c<<<4096, 256, 0, stream>>>(x, ypre, wsf + 2048, gamma, beta, out);
}

// Round 5
// 310.470 us; speedup vs baseline: 1.5905x; 1.0240x over previous
//
#include <hip/hip_runtime.h>
#include <math.h>

// Problem constants (unit_gcn): N=64, C=64, T=300, V=25, S=3
//
// ws float layout:
//   [2048, 4096)   : stats, 16 replicas x (sum[64], sumsq[64])
//   [4352, 10496)  : W-frag table ushort[12288]: frag f=((s*2+kt)*4+wv), elem lane*8+j
//   [10496, 12032) : A-frag table ushort[3072]:  frag f=(s*2+nt2)
//   byte 65536+    : ypre bf16, BLOCK-CONTIGUOUS [n][bx][o][t'][w], 61.44 MB
//
// R11: R10 failed (absmax 8.1 = O(|y|) -> operand-pairing scramble). Culprit
// isolated to the v_cvt_pk_bf16_f32 inline asm (half-placement/rounding not
// as assumed); the LDS-staged epilogue's index algebra desk-checks clean.
// Revert the pack to R9's bit-proven f2bf/OR; keep the block-contiguous
// ypre + LDS-staged epilogue (R10's write-amp fix: R9 wrote 127 MB for a
// 61.4 MB ypre via 2-byte stores into 50 B/15000 B-stride segments).

typedef __attribute__((ext_vector_type(8))) short bf16x8;
typedef __attribute__((ext_vector_type(4))) float f32x4;
typedef __attribute__((ext_vector_type(4))) ushort u16x4;
typedef __attribute__((ext_vector_type(8))) ushort u16x8;

__device__ inline ushort f2bf(float f) {
    union { float f; unsigned u; } v; v.f = f;
    unsigned r = v.u + 0x7fffu + ((v.u >> 16) & 1u);
    return (ushort)(r >> 16);
}
__device__ inline float bf2f(ushort h) {
    union { unsigned u; float f; } v; v.u = ((unsigned)h) << 16;
    return v.f;
}

// ---------------------------------------------------------------------------
// K1: 8 blocks. Normalize A (LDS), zero stats (block 0), build frag tables.
// ---------------------------------------------------------------------------
__global__ __launch_bounds__(256) void k_prep(const float* __restrict__ PA,
                                              const float* __restrict__ W,
                                              float* __restrict__ ws) {
    __shared__ float Al[1875];
    const int tid = threadIdx.x;
    const int bid = blockIdx.x;
    for (int i = tid; i < 1875; i += 256) Al[i] = PA[i];
    if (bid == 0)
        for (int i = tid; i < 2048; i += 256) ws[2048 + i] = 0.0f;
    __syncthreads();
    if (tid < 75) {
        int s = tid / 25, w = tid - s * 25;
        float ss = 0.0f;
        for (int v = 0; v < 25; ++v) {
            float p = Al[s * 625 + v * 25 + w];
            ss += p * p;
        }
        float inv = 1.0f / (sqrtf(ss) + 1e-4f);
        for (int v = 0; v < 25; ++v) Al[s * 625 + v * 25 + w] *= inv;
    }
    __syncthreads();
    int idx = bid * 256 + tid;
    if (idx < 1536) {  // W-frag: W[s][o=wv*16+col][c=kt*32+quad*8+j]
        ushort* wt = (ushort*)(ws + 4352);
        int lane = idx & 63, rest = idx >> 6;
        int wv = rest & 3, sk = rest >> 2;
        int kt = sk & 1, s = sk >> 1;
        int col = lane & 15, quad = lane >> 4;
        const float* wp = W + s * 4096 + (wv * 16 + col) * 64 + kt * 32 + quad * 8;
#pragma unroll
        for (int j = 0; j < 8; ++j) wt[idx * 8 + j] = f2bf(wp[j]);
    } else if (idx < 1920) {  // A-frag: A[s][v=quad*8+j][w=nt2*16+col], OOB->0
        ushort* at = (ushort*)(ws + 10496);
        int a = idx - 1536;
        int lane = a & 63, rest = a >> 6;
        int nt2 = rest & 1, s = rest >> 1;
        int col = lane & 15, quad = lane >> 4;
        int w = nt2 * 16 + col;
#pragma unroll
        for (int j = 0; j < 8; ++j) {
            int v = quad * 8 + j;
            float av = (v < 25 && w < 25) ? Al[s * 625 + v * 25 + w] : 0.0f;
            at[a * 8 + j] = f2bf(av);
        }
    }
}

// ---------------------------------------------------------------------------
// K2: per block one n, 4 t-steps (grid 75 x 64).
//  GEMM1 (per s,t), operands swapped: zA/zB = mfma(x_frag, w_frag) gives
//    Z^T[v][o]: o = strip+col (lane-local!), v = (quad*4+r) (+16 for zB).
//  Register re-layout: f2bf packs, 8 shfl + 4 cndmask -> zf frag
//    with elem j = Z[o=strip+col][v=quad*8+j]. No LDS round-trip.
//  GEMM2 (per s,t): yacc[t] += zf * A_s  (K=25->32 pad; zB garbage rows
//    v>=25 are killed by A-frag zeros).
//  Epilogue: stage the block's 64x100 bf16 tile in LDS (overlaying Xl,
//  dead after the s-loop) -> 800 aligned 16 B stores to block-contiguous
//  ypre. Kills R9's 2.07x partial-line write amplification.
// LDS: Xl [112 rows][72] bf16 (16.1 KB), Ys overlays it (12.8 KB).
// launch_bounds (256,4): 128-VGPR cap, live ~90 -> no spill (R7 lesson).
// ---------------------------------------------------------------------------
__global__ __launch_bounds__(256, 4) void k_main11(const float* __restrict__ x,
                                                   const float* __restrict__ ws,
                                                   ushort* __restrict__ ypre,
                                                   float* __restrict__ stats) {
    __shared__ __align__(16) ushort Xl[112 * 72];
    __shared__ float sst[128];

    const int tid = threadIdx.x;
    const int wv = tid >> 6;
    const int lane = tid & 63;
    const int col = lane & 15;
    const int quad = lane >> 4;
    const int strip = wv << 4;
    const int n = blockIdx.y;
    const int bx = blockIdx.x;
    const int t0 = bx * 4;

    // stage X (float4 loads): x[n, c, t0*25 + tv] -> Xl[tv*72 + c]
    {
        const float* xr = x + n * 480000 + t0 * 25;
        const int c = tid >> 2, part = tid & 3;
        const float4* row = (const float4*)(xr + c * 7500);
        for (int j = part; j < 25; j += 4) {
            float4 v4 = row[j];
            ushort* dst = &Xl[(j * 4) * 72 + c];
            dst[0]   = f2bf(v4.x);
            dst[72]  = f2bf(v4.y);
            dst[144] = f2bf(v4.z);
            dst[216] = f2bf(v4.w);
        }
        for (int i = tid; i < 864; i += 256) Xl[7200 + i] = 0;  // rows 100..111
    }
    __syncthreads();

    const ushort* wt = (const ushort*)(ws + 4352);
    const ushort* at = (const ushort*)(ws + 10496);

    // shfl source lanes for the quad re-layout (same col, quads 2q, 2q+1)
    const int s0l = col + ((quad & 1) << 5);
    const int s1l = s0l + 16;
    const bool hiq = quad >= 2;

    f32x4 yacc[4][2];
#pragma unroll
    for (int t = 0; t < 4; ++t)
#pragma unroll
        for (int j = 0; j < 2; ++j) yacc[t][j] = (f32x4){0.f, 0.f, 0.f, 0.f};

    for (int s = 0; s < 3; ++s) {
        // reload only the current-s fragments (16 live regs, L3-hot)
        bf16x8 wf0 = *(const bf16x8*)&wt[(((s * 2 + 0) * 4 + wv) * 64 + lane) * 8];
        bf16x8 wf1 = *(const bf16x8*)&wt[(((s * 2 + 1) * 4 + wv) * 64 + lane) * 8];
        bf16x8 af0 = *(const bf16x8*)&at[((s * 2 + 0) * 64 + lane) * 8];
        bf16x8 af1 = *(const bf16x8*)&at[((s * 2 + 1) * 64 + lane) * 8];
#pragma unroll
        for (int t = 0; t < 4; ++t) {
            const int r0 = (t * 25 + col) * 72 + (quad << 3);
            const int r1 = r0 + 16 * 72;
            bf16x8 x00 = *(const bf16x8*)&Xl[r0];
            bf16x8 x01 = *(const bf16x8*)&Xl[r0 + 32];
            bf16x8 x10 = *(const bf16x8*)&Xl[r1];
            bf16x8 x11 = *(const bf16x8*)&Xl[r1 + 32];
            // GEMM1 swapped: D[m=v][n=o] = X^T * W^T = Z^T  (bit-identical MACs)
            f32x4 zA = (f32x4){0.f, 0.f, 0.f, 0.f};
            f32x4 zB = (f32x4){0.f, 0.f, 0.f, 0.f};
            zA = __builtin_amdgcn_mfma_f32_16x16x32_bf16(x00, wf0, zA, 0, 0, 0);
            zA = __builtin_amdgcn_mfma_f32_16x16x32_bf16(x01, wf1, zA, 0, 0, 0);
            zB = __builtin_amdgcn_mfma_f32_16x16x32_bf16(x10, wf0, zB, 0, 0, 0);
            zB = __builtin_amdgcn_mfma_f32_16x16x32_bf16(x11, wf1, zB, 0, 0, 0);
            // pack with the bit-proven f2bf (R10's cvt_pk asm scrambled pairs)
            unsigned pa0 = (unsigned)f2bf(zA[0]) | ((unsigned)f2bf(zA[1]) << 16);
            unsigned pa1 = (unsigned)f2bf(zA[2]) | ((unsigned)f2bf(zA[3]) << 16);
            unsigned pb0 = (unsigned)f2bf(zB[0]) | ((unsigned)f2bf(zB[1]) << 16);
            unsigned pb1 = (unsigned)f2bf(zB[2]) | ((unsigned)f2bf(zB[3]) << 16);
            // quad re-layout: dest (col,q) word w: v-pairs (8q+2w, 8q+2w+1)
            unsigned ga0 = __shfl(pa0, s0l);
            unsigned ga1 = __shfl(pa1, s0l);
            unsigned ga2 = __shfl(pa0, s1l);
            unsigned ga3 = __shfl(pa1, s1l);
            unsigned gb0 = __shfl(pb0, s0l);
            unsigned gb1 = __shfl(pb1, s0l);
            unsigned gb2 = __shfl(pb0, s1l);
            unsigned gb3 = __shfl(pb1, s1l);
            union { unsigned u[4]; bf16x8 v; } zf;
            zf.u[0] = hiq ? gb0 : ga0;
            zf.u[1] = hiq ? gb1 : ga1;
            zf.u[2] = hiq ? gb2 : ga2;
            zf.u[3] = hiq ? gb3 : ga3;
            yacc[t][0] = __builtin_amdgcn_mfma_f32_16x16x32_bf16(zf.v, af0, yacc[t][0], 0, 0, 0);
            yacc[t][1] = __builtin_amdgcn_mfma_f32_16x16x32_bf16(zf.v, af1, yacc[t][1], 0, 0, 0);
        }
    }

    // ---- epilogue ----
    // D layout: col(lane&15)=w(+16*nt2), row(quad*4+r)=o offset.
    // Stage into Ys[o][t'*25+w] (overlays Xl -> barrier first), reduce stats,
    // then stream the 12.8 KB tile to block-contiguous ypre.
    __syncthreads();  // all waves done reading Xl
    ushort* Ys = Xl;  // 6400 ushorts used

    float ssum[4] = {0.f, 0.f, 0.f, 0.f}, ssq[4] = {0.f, 0.f, 0.f, 0.f};
    const int obase = strip + (quad << 2);
#pragma unroll
    for (int t = 0; t < 4; ++t)
#pragma unroll
        for (int nt2 = 0; nt2 < 2; ++nt2) {
            int w = nt2 * 16 + col;
            if (w < 25) {
                f32x4 f = yacc[t][nt2];
#pragma unroll
                for (int r = 0; r < 4; ++r) {
                    float yv = f[r];
                    Ys[(obase + r) * 100 + t * 25 + w] = f2bf(yv);
                    ssum[r] += yv;
                    ssq[r] = fmaf(yv, yv, ssq[r]);
                }
            }
        }
#pragma unroll
    for (int r = 0; r < 4; ++r) {
        float a = ssum[r], b = ssq[r];
        for (int m = 1; m < 16; m <<= 1) {  // reduce over the 16 w-lanes
            a += __shfl_xor(a, m, 64);
            b += __shfl_xor(b, m, 64);
        }
        if (col == 0) {  // unique (wv,quad,r) -> unique o
            sst[obase + r] = a;
            sst[64 + obase + r] = b;
        }
    }
    __syncthreads();
    // 6400 ushorts = 800 x 16 B, fully aligned, write amp 1.0
    {
        u16x8* dst = (u16x8*)(ypre + (size_t)(n * 75 + bx) * 6400);
        const u16x8* src = (const u16x8*)Ys;
        for (int i = tid; i < 800; i += 256) dst[i] = src[i];
    }
    const int rep = (bx + blockIdx.y) & 15;
    if (tid < 128) atomicAdd(&stats[rep * 128 + tid], sst[tid]);
}

// ---------------------------------------------------------------------------
// K3: out = relu(sc[o]*bf2f(ypre) + sh[o] + x). Plane-mapped: block = one
// (n,o) plane (4096 blocks). BN finalize folded in. ypre block-contiguous
// [n][bx][o][100]: plane (n,o) reads 75 chunks of 200 B. x/ypre loads stay
// cached (L2/L3-warm from k_main); out store is nontemporal (never re-read).
// ---------------------------------------------------------------------------
__global__ __launch_bounds__(256) void k_bnrelu_d(const float* __restrict__ x,
                                                  const ushort* __restrict__ ypre,
                                                  const float* __restrict__ stats,
                                                  const float* __restrict__ gamma,
                                                  const float* __restrict__ beta,
                                                  float* __restrict__ out) {
    __shared__ float bsc[2];
    const int plane = blockIdx.x;  // n*64 + o
    const int o = plane & 63;
    const int n = plane >> 6;
    const int tid = threadIdx.x;
    if (tid < 16) {
        float su = stats[tid * 128 + o];
        float sq = stats[tid * 128 + 64 + o];
#pragma unroll
        for (int m = 1; m < 16; m <<= 1) {
            su += __shfl_xor(su, m, 64);
            sq += __shfl_xor(sq, m, 64);
        }
        if (tid == 0) {
            const float invn = 1.0f / 480000.0f;  // N*T*V
            float mean = su * invn;
            float var = sq * invn - mean * mean;
            float sc = gamma[o] * rsqrtf(var + 1e-5f);
            bsc[0] = sc;
            bsc[1] = beta[o] - mean * sc;
        }
    }
    __syncthreads();
    const float sc = bsc[0], sh = bsc[1];
    const ushort* ybase = ypre + (size_t)n * 480000 + o * 100;  // + bx*6400 + inner
    const f32x4* xp = (const f32x4*)(x + (size_t)plane * 7500);
    f32x4* op = (f32x4*)(out + (size_t)plane * 7500);
    for (int j4 = tid; j4 < 1875; j4 += 256) {
        int bxi = j4 / 25;            // magic-mul, j4 = bxi*25 + r4
        int r4 = j4 - bxi * 25;
        u16x4 yv = *(const u16x4*)(ybase + bxi * 6400 + r4 * 4);
        f32x4 xx = xp[j4];
        f32x4 r;
        r.x = fmaxf(fmaf(bf2f(yv.x), sc, sh) + xx.x, 0.0f);
        r.y = fmaxf(fmaf(bf2f(yv.y), sc, sh) + xx.y, 0.0f);
        r.z = fmaxf(fmaf(bf2f(yv.z), sc, sh) + xx.z, 0.0f);
        r.w = fmaxf(fmaf(bf2f(yv.w), sc, sh) + xx.w, 0.0f);
        __builtin_nontemporal_store(r, &op[j4]);
    }
}

// ---------------------------------------------------------------------------
extern "C" void kernel_launch(void* const* d_in, const int* in_sizes, int n_in,
                              void* d_out, int out_size, void* d_ws, size_t ws_size,
                              hipStream_t stream) {
    const float* x = (const float*)d_in[0];
    const float* PA = (const float*)d_in[1];
    const float* W = (const float*)d_in[2];
    // d_in[3] = b : cancels through training-mode BN -> unused
    const float* gamma = (const float*)d_in[4];
    const float* beta = (const float*)d_in[5];
    float* wsf = (float*)d_ws;
    float* out = (float*)d_out;
    ushort* ypre = (ushort*)((char*)d_ws + 65536);

    k_prep<<<8, 256, 0, stream>>>(PA, W, wsf);
    dim3 g(75, 64);
    k_main11<<<g, 256, 0, stream>>>(x, wsf, ypre, wsf + 2048);
    k_bnrelu_d<<<4096, 256, 0, stream>>>(x, ypre, wsf + 2048, gamma, beta, out);
}